// Round 5
// baseline (493.281 us; speedup 1.0000x reference)
//
#include <hip/hip_runtime.h>
#include <cmath>

// ---------------------------------------------------------------------------
// SelfAttention: B=8, S=2048, D=768, fp32 in/out.
// R7: revert R6's 256^2 experiment (guide table: 256^2 is SLOWER than 128^2
// in the simple 2-barrier structure, 792 vs 912 TF -- my misread). Keep the
// proven R5b 128^2 kernels and add the T3-minimum 2-PHASE PREFETCH: LDS
// double-buffer (2x32KB), issue tile t+1's global_load_lds into buf^1 BEFORE
// the MFMA cluster on buf, single __syncthreads per K-step (its vmcnt(0)
// drain now lands after ~16 ds_read + 32 MFMA of work instead of after
// nothing). Rationale: measured OccupancyPercent ~16% (~5 waves/CU) -- too
// few waves for implicit overlap to hide the stage drain (the regime where
// learn_hip found explicit dbuf neutral was ~12 waves/CU). Also: QKV fused
// into ONE gemm128 launch at unchanged geometry (grid (128,18); weight stack
// [2304][768] is contiguous in scratch; group = by/6).
// Accumulation order per output element unchanged -> bit-identical result.
//
// Memory plan (ws use = 92.3 MB when Pb path taken, else 25.2 MB):
//   d_out out0 [0,50.3MB):    Qb bf16 [16384][768], Kb bf16 [16384][768]
//   d_out out1 [50.3,184.5MB): pre-scores scratch: xb bf16 [16384][768],
//                              Wqb/Wkb/Wvb bf16 [768][768] (contiguous!)
//   d_ws:                      Vt bf16 [8][768][2048]  (25.2 MB)
//                              Pb bf16 [8][2048][2048] (67.1 MB, optional)
// ---------------------------------------------------------------------------

typedef __bf16 v8bf __attribute__((ext_vector_type(8)));
typedef float  v4f  __attribute__((ext_vector_type(4)));
typedef unsigned short u16;

__device__ __forceinline__ u16 f2bf(float f) {
  union { float f; unsigned u; } v; v.f = f;
  unsigned r = v.u + 0x7fffu + ((v.u >> 16) & 1u);   // round-to-nearest-even
  return (u16)(r >> 16);
}

__device__ __forceinline__ uint4 pack8(const float* __restrict__ src) {
  float4 f0 = *(const float4*)src;
  float4 f1 = *(const float4*)(src + 4);
  union { uint4 u; u16 h[8]; } pk;
  pk.h[0] = f2bf(f0.x); pk.h[1] = f2bf(f0.y); pk.h[2] = f2bf(f0.z); pk.h[3] = f2bf(f0.w);
  pk.h[4] = f2bf(f1.x); pk.h[5] = f2bf(f1.y); pk.h[6] = f2bf(f1.z); pk.h[7] = f2bf(f1.w);
  return pk.u;
}

// async 16B global -> LDS (wave-uniform base + lane*16 layout)
__device__ __forceinline__ void gl_lds16(const void* g, void* l) {
  __builtin_amdgcn_global_load_lds(
      (const __attribute__((address_space(1))) unsigned*)g,
      (__attribute__((address_space(3))) unsigned*)l, 16, 0, 0);
}

enum { OUT_F32 = 0, OUT_QKV = 1 };

constexpr int BM = 128, BN = 128, BK = 64;
constexpr int TILE = BM * BK;   // u16 elements per buffer

// C[M,N] = alpha * A[M,K] * B[N,K]^T  (NT). B always bf16. A bf16 or fp32.
// grid: (M/128, N/128, batch); 256 threads = 4 waves in 2x2, each 64x64 out.
// LDS: DOUBLE-BUFFERED tiles [128 rows][8 chunks of 16B]; slot cpos holds
// global chunk cpos^(row&7) (XOR swizzle -> conflict-free fragment reads).
// 2-phase schedule: stage(t+1 -> buf^1) issued BEFORE MFMA(t, buf); one
// __syncthreads (vmcnt+lgkm drain) per K-step.
// OUT_QKV: B = [2304][768] = [Wq;Wk;Wv]; group=n0/768 routes to C0/C1/C2(Vt).
template <bool A_F32, int MODE>
__global__ __launch_bounds__(256)
void gemm128(const void* __restrict__ Ag_, const void* __restrict__ Bg_,
             void* __restrict__ C0, void* __restrict__ C1, void* __restrict__ C2,
             int K, int lda, int ldb, int ldc,
             long long sA, long long sB, long long sC, float alpha) {
  __shared__ u16 As[2 * TILE];
  __shared__ u16 Bs[2 * TILE];

  const int z  = blockIdx.z;
  const int m0 = blockIdx.x * BM;
  const int n0 = blockIdx.y * BN;

  const int t    = threadIdx.x;
  const int lane = t & 63;
  const int w    = t >> 6;
  const int wm   = (w & 1) * 64;     // wave's 64x64 quadrant
  const int wn   = (w >> 1) * 64;
  const int fr   = lane & 15;        // fragment row
  const int quad = lane >> 4;        // fragment k chunk (16B) within 32-elem k

  const u16* Bp = (const u16*)Bg_ + (size_t)z * (size_t)sB;

  v4f acc[4][4];
#pragma unroll
  for (int i = 0; i < 4; ++i)
#pragma unroll
    for (int j = 0; j < 4; ++j) acc[i][j] = (v4f){0.f, 0.f, 0.f, 0.f};

  // --- staging helper (issues 8 async loads, or 4 loads + pack for A_F32) ---
  auto stage = [&](int kt, int buf) {
#pragma unroll
    for (int j = 0; j < 4; ++j) {
      const int s   = (w * 4 + j) * 64 + lane;        // LDS 16B-slot, 0..1023
      const int row = s >> 3;
      const int gc  = (s & 7) ^ (row & 7);            // source chunk (swizzled)
      gl_lds16(Bp + (size_t)(n0 + row) * ldb + kt + gc * 8,
               &Bs[buf * TILE + s * 8]);
    }
    if constexpr (A_F32) {
      const float* Ap = (const float*)Ag_ + (size_t)z * (size_t)sA;
#pragma unroll
      for (int j = 0; j < 4; ++j) {
        const int g   = j * 256 + t;                  // source-linear chunk id
        const int row = g >> 3, gc = g & 7;
        const int s   = (g & ~7) | (gc ^ (row & 7));  // swizzled LDS slot
        uint4 pk = pack8(Ap + (size_t)(m0 + row) * lda + kt + gc * 8);
        *(uint4*)&As[buf * TILE + s * 8] = pk;
      }
    } else {
      const u16* Ap = (const u16*)Ag_ + (size_t)z * (size_t)sA;
#pragma unroll
      for (int j = 0; j < 4; ++j) {
        const int s   = (w * 4 + j) * 64 + lane;
        const int row = s >> 3;
        const int gc  = (s & 7) ^ (row & 7);
        gl_lds16(Ap + (size_t)(m0 + row) * lda + kt + gc * 8,
                 &As[buf * TILE + s * 8]);
      }
    }
  };

  // prologue: stage tile 0 into buf 0
  stage(0, 0);
  __syncthreads();   // drains vmcnt (async loads) + lgkmcnt (A_F32 ds_write)

  int cur = 0;
  for (int kt = 0; kt < K; kt += BK) {
    // phase 1: issue next tile's loads into the other buffer (hidden under MFMA)
    if (kt + BK < K) stage(kt + BK, cur ^ 1);

    // phase 2: 32 MFMAs per wave over BK=64 from buf[cur]
    const u16* Ab = &As[cur * TILE];
    const u16* Bb = &Bs[cur * TILE];
#pragma unroll
    for (int kk = 0; kk < BK; kk += 32) {
      const int kc = (kk >> 3) + quad;                // chunk 0..7
      v8bf af[4], bv[4];
#pragma unroll
      for (int i = 0; i < 4; ++i) {
        const int ra = wm + i * 16 + fr;              // (ra&7)==(fr&7)
        const int rb = wn + i * 16 + fr;
        af[i] = *(const v8bf*)&Ab[(ra * 8 + (kc ^ (fr & 7))) * 8];
        bv[i] = *(const v8bf*)&Bb[(rb * 8 + (kc ^ (fr & 7))) * 8];
      }
#pragma unroll
      for (int mi = 0; mi < 4; ++mi)
#pragma unroll
        for (int ni = 0; ni < 4; ++ni)
          acc[mi][ni] =
              __builtin_amdgcn_mfma_f32_16x16x32_bf16(af[mi], bv[ni], acc[mi][ni], 0, 0, 0);
    }
    __syncthreads();   // one barrier per K-step: drains vmcnt(0)+lgkmcnt(0)
    cur ^= 1;
  }

  // epilogue: C/D layout col=lane&15, row=(lane>>4)*4+reg
  const int r0 = (lane >> 4) * 4;
#pragma unroll
  for (int mi = 0; mi < 4; ++mi) {
#pragma unroll
    for (int ni = 0; ni < 4; ++ni) {
      v4f v = acc[mi][ni];
      const int grow0 = m0 + wm + mi * 16 + r0;
      const int gcol  = n0 + wn + ni * 16 + fr;
      if constexpr (MODE == OUT_F32) {
        float* C = (float*)C0 + (size_t)z * (size_t)sC;
#pragma unroll
        for (int r = 0; r < 4; ++r)
          C[(size_t)(grow0 + r) * ldc + gcol] = v[r] * alpha;
      } else {  // OUT_QKV: route by weight group (n0 mult of 128, 768=6*128)
        const int grp  = n0 / 768;             // 0=Q, 1=K, 2=V
        const int lcol = (n0 - grp * 768) + wn + ni * 16 + fr;
        if (grp == 0) {
          u16* C = (u16*)C0;
#pragma unroll
          for (int r = 0; r < 4; ++r)
            C[(size_t)(grow0 + r) * 768 + lcol] = f2bf(v[r]);
        } else if (grp == 1) {
          u16* C = (u16*)C1;
#pragma unroll
          for (int r = 0; r < 4; ++r)
            C[(size_t)(grow0 + r) * 768 + lcol] = f2bf(v[r]);
        } else {  // Vt[b][d][s]: rows are 4 consecutive s
          u16* C = (u16*)C2;
          size_t base = (size_t)(grow0 >> 11) * (768ull * 2048ull) +
                        (size_t)lcol * 2048ull + (size_t)(grow0 & 2047);
          ushort4 st;
          st.x = f2bf(v[0]); st.y = f2bf(v[1]); st.z = f2bf(v[2]); st.w = f2bf(v[3]);
          *(ushort4*)&C[base] = st;
        }
      }
    }
  }
}

// fp32 -> bf16 copy, 8 elements/thread
__global__ __launch_bounds__(256)
void cvt_bf16(const float* __restrict__ src, u16* __restrict__ dst, int n8) {
  const int i = blockIdx.x * 256 + threadIdx.x;
  if (i < n8) *(uint4*)(dst + (size_t)i * 8) = pack8(src + (size_t)i * 8);
}

// three small weight matrices in one launch (blockIdx.y selects)
__global__ __launch_bounds__(256)
void cvt3_bf16(const float* __restrict__ s0, const float* __restrict__ s1,
               const float* __restrict__ s2, u16* __restrict__ d0,
               u16* __restrict__ d1, u16* __restrict__ d2, int n8) {
  const float* s = blockIdx.y == 0 ? s0 : blockIdx.y == 1 ? s1 : s2;
  u16*         d = blockIdx.y == 0 ? d0 : blockIdx.y == 1 ? d1 : d2;
  const int i = blockIdx.x * 256 + threadIdx.x;
  if (i < n8) *(uint4*)(d + (size_t)i * 8) = pack8(s + (size_t)i * 8);
}

// in-place softmax over rows of 2048 fp32; one block per row.
// EMIT: also write a bf16 copy of the row to pb (PV's A operand).
template <bool EMIT>
__global__ __launch_bounds__(256) void softmax_rows(float* __restrict__ w,
                                                    u16* __restrict__ pb) {
  float* p = w + (size_t)blockIdx.x * 2048;
  const int t = threadIdx.x;
  float4 a = *(float4*)(p + t * 4);
  float4 b = *(float4*)(p + 1024 + t * 4);

  float mx = fmaxf(fmaxf(fmaxf(a.x, a.y), fmaxf(a.z, a.w)),
                   fmaxf(fmaxf(b.x, b.y), fmaxf(b.z, b.w)));
#pragma unroll
  for (int off = 32; off; off >>= 1) mx = fmaxf(mx, __shfl_xor(mx, off));
  __shared__ float red[4];
  const int wid = t >> 6, ln = t & 63;
  if (ln == 0) red[wid] = mx;
  __syncthreads();
  mx = fmaxf(fmaxf(red[0], red[1]), fmaxf(red[2], red[3]));

  a.x = __expf(a.x - mx); a.y = __expf(a.y - mx);
  a.z = __expf(a.z - mx); a.w = __expf(a.w - mx);
  b.x = __expf(b.x - mx); b.y = __expf(b.y - mx);
  b.z = __expf(b.z - mx); b.w = __expf(b.w - mx);

  float s = a.x + a.y + a.z + a.w + b.x + b.y + b.z + b.w;
#pragma unroll
  for (int off = 32; off; off >>= 1) s += __shfl_xor(s, off);
  __syncthreads();
  if (ln == 0) red[wid] = s;
  __syncthreads();
  s = red[0] + red[1] + red[2] + red[3];

  const float inv = 1.0f / s;
  a.x *= inv; a.y *= inv; a.z *= inv; a.w *= inv;
  b.x *= inv; b.y *= inv; b.z *= inv; b.w *= inv;
  *(float4*)(p + t * 4) = a;
  *(float4*)(p + 1024 + t * 4) = b;

  if constexpr (EMIT) {
    u16* q = pb + (size_t)blockIdx.x * 2048;
    ushort4 ha, hb;
    ha.x = f2bf(a.x); ha.y = f2bf(a.y); ha.z = f2bf(a.z); ha.w = f2bf(a.w);
    hb.x = f2bf(b.x); hb.y = f2bf(b.y); hb.z = f2bf(b.z); hb.w = f2bf(b.w);
    *(ushort4*)(q + t * 4) = ha;
    *(ushort4*)(q + 1024 + t * 4) = hb;
  }
}

extern "C" void kernel_launch(void* const* d_in, const int* in_sizes, int n_in,
                              void* d_out, int out_size, void* d_ws, size_t ws_size,
                              hipStream_t stream) {
  const float* x  = (const float*)d_in[0];
  const float* Wq = (const float*)d_in[1];
  const float* Wk = (const float*)d_in[2];
  const float* Wv = (const float*)d_in[3];
  float* out = (float*)d_out;
  float* wts = out + 8ull * 2048 * 768;   // out1 region (attention weights)

  // bf16 scratch inside d_out (see header comment)
  u16* Qb  = (u16*)d_out;                 // out0: [16384][768]
  u16* Kb  = Qb + 16384ull * 768;         //       [16384][768]
  u16* xb  = (u16*)wts;                   // out1 scratch: [16384][768]
  u16* Wqb = xb + 16384ull * 768;         //               [768][768] x3 (contig)
  u16* Wkb = Wqb + 768ull * 768;
  u16* Wvb = Wkb + 768ull * 768;
  u16* Vt  = (u16*)d_ws;                  // ws: [8][768][2048] (25.2 MB)
  u16* Pb  = Vt + 8ull * 768 * 2048;      // ws: [8][2048][2048] bf16 (67.1 MB)

  const size_t VT_BYTES = 8ull * 768 * 2048 * 2;
  const size_t PB_BYTES = 8ull * 2048 * 2048 * 2;
  const bool   pb_ok    = ws_size >= VT_BYTES + PB_BYTES;

  const dim3 blk(256, 1, 1);
  const float isq = 1.0f / sqrtf(768.0f);

  // pre-convert inputs to bf16
  cvt_bf16<<<dim3(6144, 1, 1), blk, 0, stream>>>(x, xb, 16384 * 768 / 8);
  cvt3_bf16<<<dim3(288, 3, 1), blk, 0, stream>>>(Wq, Wk, Wv, Wqb, Wkb, Wvb,
                                                 768 * 768 / 8);

  // fused QKV: M=16384, N=2304 (=[Wq;Wk;Wv]), K=768, one launch, 128^2 tiles
  gemm128<false, OUT_QKV><<<dim3(128, 18, 1), blk, 0, stream>>>(
      xb, Wqb, (void*)Qb, (void*)Kb, (void*)Vt, 768, 768, 768, 768,
      0, 0, 0, 1.0f);

  // scores: per batch M=N=2048, K=768 -> wts fp32 * 1/sqrt(D)
  gemm128<false, OUT_F32><<<dim3(16, 16, 8), blk, 0, stream>>>(
      Qb, Kb, (void*)wts, nullptr, nullptr, 768, 768, 768, 2048,
      2048ll * 768, 2048ll * 768, 2048ll * 2048, isq);

  // softmax in place over 16384 rows (+ bf16 emit for PV if ws allows)
  if (pb_ok) {
    softmax_rows<true><<<dim3(16384, 1, 1), blk, 0, stream>>>(wts, Pb);
    // PV fast path: all-bf16. per batch M=2048, N=768, K=2048
    gemm128<false, OUT_F32><<<dim3(16, 6, 8), blk, 0, stream>>>(
        Pb, Vt, (void*)out, nullptr, nullptr, 2048, 2048, 2048, 768,
        2048ll * 2048, 768ll * 2048, 2048ll * 768, 1.0f);
  } else {
    softmax_rows<false><<<dim3(16384, 1, 1), blk, 0, stream>>>(wts, nullptr);
    // fallback: A=attn fp32 (convert-staged in-GEMM)
    gemm128<true, OUT_F32><<<dim3(16, 6, 8), blk, 0, stream>>>(
        wts, Vt, (void*)out, nullptr, nullptr, 2048, 2048, 2048, 768,
        2048ll * 2048, 768ll * 2048, 2048ll * 768, 1.0f);
  }
}

// Round 6
// 485.978 us; speedup vs baseline: 1.0150x; 1.0150x over previous
//
#include <hip/hip_runtime.h>
#include <cmath>

// ---------------------------------------------------------------------------
// SelfAttention: B=8, S=2048, D=768, fp32 in/out.
// R8: revert R7's LDS double-buffer (64KB LDS halved blocks/CU and the single
// __syncthreads still drains vmcnt(0) -> lost TLP, gained no ILP; 493us).
// Back to the R5b-proven single-buffer 2-barrier gemm128 (462us baseline) and
// add the two verified-safe pieces: (1) bijective chunked XCD swizzle on all
// GEMM grids (R6-verified correct); chunks align exactly: scores 2048wg ->
// 256/XCD = one batch's 6MB Q+K per XCD L2; PV 768wg -> one batch/XCD; QKV
// weight tile stays L2-hot per chunk. We are stage-latency-bound (MfmaUtil
// 17.8%, HBM 24%) so L2-hit staging (~200cy vs ~900cy) directly shortens the
// barrier drain. (2) QKV fused into ONE launch (R7-verified OUT_QKV epilogue;
// grid (128,18), weight stack [2304][768] contiguous in scratch).
// Accumulation order per output element unchanged -> bit-identical result.
//
// Memory plan (ws use = 92.3 MB when Pb path taken, else 25.2 MB):
//   d_out out0 [0,50.3MB):    Qb bf16 [16384][768], Kb bf16 [16384][768]
//   d_out out1 [50.3,184.5MB): pre-scores scratch: xb bf16 [16384][768],
//                              Wqb/Wkb/Wvb bf16 [768][768] (contiguous!)
//   d_ws:                      Vt bf16 [8][768][2048]  (25.2 MB)
//                              Pb bf16 [8][2048][2048] (67.1 MB, optional)
// ---------------------------------------------------------------------------

typedef __bf16 v8bf __attribute__((ext_vector_type(8)));
typedef float  v4f  __attribute__((ext_vector_type(4)));
typedef unsigned short u16;

__device__ __forceinline__ u16 f2bf(float f) {
  union { float f; unsigned u; } v; v.f = f;
  unsigned r = v.u + 0x7fffu + ((v.u >> 16) & 1u);   // round-to-nearest-even
  return (u16)(r >> 16);
}

__device__ __forceinline__ uint4 pack8(const float* __restrict__ src) {
  float4 f0 = *(const float4*)src;
  float4 f1 = *(const float4*)(src + 4);
  union { uint4 u; u16 h[8]; } pk;
  pk.h[0] = f2bf(f0.x); pk.h[1] = f2bf(f0.y); pk.h[2] = f2bf(f0.z); pk.h[3] = f2bf(f0.w);
  pk.h[4] = f2bf(f1.x); pk.h[5] = f2bf(f1.y); pk.h[6] = f2bf(f1.z); pk.h[7] = f2bf(f1.w);
  return pk.u;
}

// async 16B global -> LDS (wave-uniform base + lane*16 layout)
__device__ __forceinline__ void gl_lds16(const void* g, void* l) {
  __builtin_amdgcn_global_load_lds(
      (const __attribute__((address_space(1))) unsigned*)g,
      (__attribute__((address_space(3))) unsigned*)l, 16, 0, 0);
}

enum { OUT_F32 = 0, OUT_QKV = 1 };

constexpr int BM = 128, BN = 128, BK = 64;

// C[M,N] = alpha * A[M,K] * B[N,K]^T  (NT). B always bf16. A bf16 or fp32.
// logical grid (M/128, N/128, batch) linearized x-fastest, then chunked XCD
// swizzle: physical block i (HW: XCD i%8) takes logical lid (i%8)*(nwg/8) +
// i/8, so each XCD owns a CONTIGUOUS logical chunk (L2 locality).
// 256 threads = 4 waves in 2x2, each 64x64 out. LDS tile = [128 rows][8
// chunks of 16B]; slot cpos holds global chunk cpos^(row&7) (XOR swizzle ->
// conflict-free fragment reads). Single-buffered, 2 barriers per K-step.
// OUT_QKV: B = [2304][768] = [Wq;Wk;Wv]; grp=n0/768 routes to C0/C1/C2(Vt).
template <bool A_F32, int MODE>
__global__ __launch_bounds__(256)
void gemm128(const void* __restrict__ Ag_, const void* __restrict__ Bg_,
             void* __restrict__ C0, void* __restrict__ C1, void* __restrict__ C2,
             int K, int lda, int ldb, int ldc,
             long long sA, long long sB, long long sC, float alpha) {
  __shared__ u16 As[BM * BK];
  __shared__ u16 Bs[BN * BK];

  // --- chunked XCD swizzle (bijective; nwg % 8 == 0 in all our launches) ---
  const int gx = gridDim.x, gy = gridDim.y;
  const int nwg = gx * gy * gridDim.z;
  int lid = blockIdx.x + gx * (blockIdx.y + gy * blockIdx.z);
  if ((nwg & 7) == 0) {
    const int cpx = nwg >> 3;
    lid = (lid & 7) * cpx + (lid >> 3);
  }
  const int bx  = lid % gx;
  const int byz = lid / gx;
  const int by  = byz % gy;
  const int z   = byz / gy;

  const int m0 = bx * BM;
  const int n0 = by * BN;

  const int t    = threadIdx.x;
  const int lane = t & 63;
  const int w    = t >> 6;
  const int wm   = (w & 1) * 64;     // wave's 64x64 quadrant
  const int wn   = (w >> 1) * 64;
  const int fr   = lane & 15;        // fragment row
  const int quad = lane >> 4;        // fragment k chunk (16B) within 32-elem k

  const u16* Bp = (const u16*)Bg_ + (size_t)z * (size_t)sB;

  v4f acc[4][4];
#pragma unroll
  for (int i = 0; i < 4; ++i)
#pragma unroll
    for (int j = 0; j < 4; ++j) acc[i][j] = (v4f){0.f, 0.f, 0.f, 0.f};

  for (int kt = 0; kt < K; kt += BK) {
    // --- stage B tile: LDS slot s (=row*8+cpos) gets global chunk cpos^(row&7)
#pragma unroll
    for (int j = 0; j < 4; ++j) {
      const int s   = (w * 4 + j) * 64 + lane;        // LDS 16B-slot, 0..1023
      const int row = s >> 3;
      const int gc  = (s & 7) ^ (row & 7);            // source chunk (swizzled)
      gl_lds16(Bp + (size_t)(n0 + row) * ldb + kt + gc * 8, &Bs[s * 8]);
    }
    // --- stage A tile ---
    if constexpr (A_F32) {
      const float* Ap = (const float*)Ag_ + (size_t)z * (size_t)sA;
#pragma unroll
      for (int j = 0; j < 4; ++j) {
        const int g   = j * 256 + t;                  // source-linear chunk id
        const int row = g >> 3, gc = g & 7;
        const int s   = (g & ~7) | (gc ^ (row & 7));  // swizzled LDS slot
        uint4 pk = pack8(Ap + (size_t)(m0 + row) * lda + kt + gc * 8);
        *(uint4*)&As[s * 8] = pk;
      }
    } else {
      const u16* Ap = (const u16*)Ag_ + (size_t)z * (size_t)sA;
#pragma unroll
      for (int j = 0; j < 4; ++j) {
        const int s   = (w * 4 + j) * 64 + lane;
        const int row = s >> 3;
        const int gc  = (s & 7) ^ (row & 7);
        gl_lds16(Ap + (size_t)(m0 + row) * lda + kt + gc * 8, &As[s * 8]);
      }
    }
    __syncthreads();   // drains vmcnt (global_load_lds) + lgkmcnt (ds_write)

    // --- 32 MFMAs per wave over BK=64 ---
#pragma unroll
    for (int kk = 0; kk < BK; kk += 32) {
      const int kc = (kk >> 3) + quad;                // chunk 0..7
      v8bf af[4], bv[4];
#pragma unroll
      for (int i = 0; i < 4; ++i) {
        const int ra = wm + i * 16 + fr;              // (ra&7)==(fr&7)
        const int rb = wn + i * 16 + fr;
        af[i] = *(const v8bf*)&As[(ra * 8 + (kc ^ (fr & 7))) * 8];
        bv[i] = *(const v8bf*)&Bs[(rb * 8 + (kc ^ (fr & 7))) * 8];
      }
#pragma unroll
      for (int mi = 0; mi < 4; ++mi)
#pragma unroll
        for (int ni = 0; ni < 4; ++ni)
          acc[mi][ni] =
              __builtin_amdgcn_mfma_f32_16x16x32_bf16(af[mi], bv[ni], acc[mi][ni], 0, 0, 0);
    }
    __syncthreads();
  }

  // epilogue: C/D layout col=lane&15, row=(lane>>4)*4+reg
  const int r0 = (lane >> 4) * 4;
#pragma unroll
  for (int mi = 0; mi < 4; ++mi) {
#pragma unroll
    for (int ni = 0; ni < 4; ++ni) {
      v4f v = acc[mi][ni];
      const int grow0 = m0 + wm + mi * 16 + r0;
      const int gcol  = n0 + wn + ni * 16 + fr;
      if constexpr (MODE == OUT_F32) {
        float* C = (float*)C0 + (size_t)z * (size_t)sC;
#pragma unroll
        for (int r = 0; r < 4; ++r)
          C[(size_t)(grow0 + r) * ldc + gcol] = v[r] * alpha;
      } else {  // OUT_QKV: route by weight group (n0 mult of 128, 768=6*128)
        const int grp  = n0 / 768;             // 0=Q, 1=K, 2=V
        const int lcol = gcol - grp * 768;
        if (grp == 0) {
          u16* C = (u16*)C0;
#pragma unroll
          for (int r = 0; r < 4; ++r)
            C[(size_t)(grow0 + r) * 768 + lcol] = f2bf(v[r]);
        } else if (grp == 1) {
          u16* C = (u16*)C1;
#pragma unroll
          for (int r = 0; r < 4; ++r)
            C[(size_t)(grow0 + r) * 768 + lcol] = f2bf(v[r]);
        } else {  // Vt[b][d][s]: rows are 4 consecutive s
          u16* C = (u16*)C2;
          size_t base = (size_t)(grow0 >> 11) * (768ull * 2048ull) +
                        (size_t)lcol * 2048ull + (size_t)(grow0 & 2047);
          ushort4 st;
          st.x = f2bf(v[0]); st.y = f2bf(v[1]); st.z = f2bf(v[2]); st.w = f2bf(v[3]);
          *(ushort4*)&C[base] = st;
        }
      }
    }
  }
}

// fp32 -> bf16 copy, 8 elements/thread
__global__ __launch_bounds__(256)
void cvt_bf16(const float* __restrict__ src, u16* __restrict__ dst, int n8) {
  const int i = blockIdx.x * 256 + threadIdx.x;
  if (i < n8) *(uint4*)(dst + (size_t)i * 8) = pack8(src + (size_t)i * 8);
}

// three small weight matrices in one launch (blockIdx.y selects)
__global__ __launch_bounds__(256)
void cvt3_bf16(const float* __restrict__ s0, const float* __restrict__ s1,
               const float* __restrict__ s2, u16* __restrict__ d0,
               u16* __restrict__ d1, u16* __restrict__ d2, int n8) {
  const float* s = blockIdx.y == 0 ? s0 : blockIdx.y == 1 ? s1 : s2;
  u16*         d = blockIdx.y == 0 ? d0 : blockIdx.y == 1 ? d1 : d2;
  const int i = blockIdx.x * 256 + threadIdx.x;
  if (i < n8) *(uint4*)(d + (size_t)i * 8) = pack8(s + (size_t)i * 8);
}

// in-place softmax over rows of 2048 fp32; one block per row.
// EMIT: also write a bf16 copy of the row to pb (PV's A operand).
template <bool EMIT>
__global__ __launch_bounds__(256) void softmax_rows(float* __restrict__ w,
                                                    u16* __restrict__ pb) {
  float* p = w + (size_t)blockIdx.x * 2048;
  const int t = threadIdx.x;
  float4 a = *(float4*)(p + t * 4);
  float4 b = *(float4*)(p + 1024 + t * 4);

  float mx = fmaxf(fmaxf(fmaxf(a.x, a.y), fmaxf(a.z, a.w)),
                   fmaxf(fmaxf(b.x, b.y), fmaxf(b.z, b.w)));
#pragma unroll
  for (int off = 32; off; off >>= 1) mx = fmaxf(mx, __shfl_xor(mx, off));
  __shared__ float red[4];
  const int wid = t >> 6, ln = t & 63;
  if (ln == 0) red[wid] = mx;
  __syncthreads();
  mx = fmaxf(fmaxf(red[0], red[1]), fmaxf(red[2], red[3]));

  a.x = __expf(a.x - mx); a.y = __expf(a.y - mx);
  a.z = __expf(a.z - mx); a.w = __expf(a.w - mx);
  b.x = __expf(b.x - mx); b.y = __expf(b.y - mx);
  b.z = __expf(b.z - mx); b.w = __expf(b.w - mx);

  float s = a.x + a.y + a.z + a.w + b.x + b.y + b.z + b.w;
#pragma unroll
  for (int off = 32; off; off >>= 1) s += __shfl_xor(s, off);
  __syncthreads();
  if (ln == 0) red[wid] = s;
  __syncthreads();
  s = red[0] + red[1] + red[2] + red[3];

  const float inv = 1.0f / s;
  a.x *= inv; a.y *= inv; a.z *= inv; a.w *= inv;
  b.x *= inv; b.y *= inv; b.z *= inv; b.w *= inv;
  *(float4*)(p + t * 4) = a;
  *(float4*)(p + 1024 + t * 4) = b;

  if constexpr (EMIT) {
    u16* q = pb + (size_t)blockIdx.x * 2048;
    ushort4 ha, hb;
    ha.x = f2bf(a.x); ha.y = f2bf(a.y); ha.z = f2bf(a.z); ha.w = f2bf(a.w);
    hb.x = f2bf(b.x); hb.y = f2bf(b.y); hb.z = f2bf(b.z); hb.w = f2bf(b.w);
    *(ushort4*)(q + t * 4) = ha;
    *(ushort4*)(q + 1024 + t * 4) = hb;
  }
}

extern "C" void kernel_launch(void* const* d_in, const int* in_sizes, int n_in,
                              void* d_out, int out_size, void* d_ws, size_t ws_size,
                              hipStream_t stream) {
  const float* x  = (const float*)d_in[0];
  const float* Wq = (const float*)d_in[1];
  const float* Wk = (const float*)d_in[2];
  const float* Wv = (const float*)d_in[3];
  float* out = (float*)d_out;
  float* wts = out + 8ull * 2048 * 768;   // out1 region (attention weights)

  // bf16 scratch inside d_out (see header comment)
  u16* Qb  = (u16*)d_out;                 // out0: [16384][768]
  u16* Kb  = Qb + 16384ull * 768;         //       [16384][768]
  u16* xb  = (u16*)wts;                   // out1 scratch: [16384][768]
  u16* Wqb = xb + 16384ull * 768;         //               [768][768] x3 (contig)
  u16* Wkb = Wqb + 768ull * 768;
  u16* Wvb = Wkb + 768ull * 768;
  u16* Vt  = (u16*)d_ws;                  // ws: [8][768][2048] (25.2 MB)
  u16* Pb  = Vt + 8ull * 768 * 2048;      // ws: [8][2048][2048] bf16 (67.1 MB)

  const size_t VT_BYTES = 8ull * 768 * 2048 * 2;
  const size_t PB_BYTES = 8ull * 2048 * 2048 * 2;
  const bool   pb_ok    = ws_size >= VT_BYTES + PB_BYTES;

  const dim3 blk(256, 1, 1);
  const float isq = 1.0f / sqrtf(768.0f);

  // pre-convert inputs to bf16
  cvt_bf16<<<dim3(6144, 1, 1), blk, 0, stream>>>(x, xb, 16384 * 768 / 8);
  cvt3_bf16<<<dim3(288, 3, 1), blk, 0, stream>>>(Wq, Wk, Wv, Wqb, Wkb, Wvb,
                                                 768 * 768 / 8);

  // fused QKV: M=16384, N=2304 (=[Wq;Wk;Wv]), K=768, one launch, 128^2 tiles
  gemm128<false, OUT_QKV><<<dim3(128, 18, 1), blk, 0, stream>>>(
      xb, Wqb, (void*)Qb, (void*)Kb, (void*)Vt, 768, 768, 768, 768,
      0, 0, 0, 1.0f);

  // scores: per batch M=N=2048, K=768 -> wts fp32 * 1/sqrt(D)
  // swizzle: 2048 wg -> 256/XCD = exactly one batch per XCD L2
  gemm128<false, OUT_F32><<<dim3(16, 16, 8), blk, 0, stream>>>(
      Qb, Kb, (void*)wts, nullptr, nullptr, 768, 768, 768, 2048,
      2048ll * 768, 2048ll * 768, 2048ll * 2048, isq);

  // softmax in place over 16384 rows (+ bf16 emit for PV if ws allows)
  if (pb_ok) {
    softmax_rows<true><<<dim3(16384, 1, 1), blk, 0, stream>>>(wts, Pb);
    // PV fast path: all-bf16. per batch M=2048, N=768, K=2048
    // swizzle: 768 wg -> 96/XCD = exactly one batch per XCD
    gemm128<false, OUT_F32><<<dim3(16, 6, 8), blk, 0, stream>>>(
        Pb, Vt, (void*)out, nullptr, nullptr, 2048, 2048, 2048, 768,
        2048ll * 2048, 768ll * 2048, 2048ll * 768, 1.0f);
  } else {
    softmax_rows<false><<<dim3(16384, 1, 1), blk, 0, stream>>>(wts, nullptr);
    // fallback: A=attn fp32 (convert-staged in-GEMM)
    gemm128<true, OUT_F32><<<dim3(16, 6, 8), blk, 0, stream>>>(
        wts, Vt, (void*)out, nullptr, nullptr, 2048, 2048, 2048, 768,
        2048ll * 2048, 768ll * 2048, 2048ll * 768, 1.0f);
  }
}

// Round 7
// 448.600 us; speedup vs baseline: 1.0996x; 1.0833x over previous
//
#include <hip/hip_runtime.h>
#include <cmath>

// ---------------------------------------------------------------------------
// SelfAttention: B=8, S=2048, D=768, fp32 in/out.
// R9: deconfound R8's bundled regression. R8 = R5b + {XCD swizzle, QKV
// fusion} regressed 462->486; the guide's m160 measurement says chunked XCD
// swizzle COSTS ~2% when operands are L3-fit (all ours are <=50MB). So:
// exact R5b structure (single-buffered 32KB LDS, 2-barrier K-loop, NO
// swizzle) + ONLY the QKV single-launch fusion (mechanism: -2 launches,
// identical per-block work; epilogue HW-verified in R7+R8).
// Accumulation order per output element unchanged -> bit-identical result.
//
// Memory plan (ws use = 92.3 MB when Pb path taken, else 25.2 MB):
//   d_out out0 [0,50.3MB):    Qb bf16 [16384][768], Kb bf16 [16384][768]
//   d_out out1 [50.3,184.5MB): pre-scores scratch: xb bf16 [16384][768],
//                              Wqb/Wkb/Wvb bf16 [768][768] (contiguous!)
//   d_ws:                      Vt bf16 [8][768][2048]  (25.2 MB)
//                              Pb bf16 [8][2048][2048] (67.1 MB, optional)
// ---------------------------------------------------------------------------

typedef __bf16 v8bf __attribute__((ext_vector_type(8)));
typedef float  v4f  __attribute__((ext_vector_type(4)));
typedef unsigned short u16;

__device__ __forceinline__ u16 f2bf(float f) {
  union { float f; unsigned u; } v; v.f = f;
  unsigned r = v.u + 0x7fffu + ((v.u >> 16) & 1u);   // round-to-nearest-even
  return (u16)(r >> 16);
}

__device__ __forceinline__ uint4 pack8(const float* __restrict__ src) {
  float4 f0 = *(const float4*)src;
  float4 f1 = *(const float4*)(src + 4);
  union { uint4 u; u16 h[8]; } pk;
  pk.h[0] = f2bf(f0.x); pk.h[1] = f2bf(f0.y); pk.h[2] = f2bf(f0.z); pk.h[3] = f2bf(f0.w);
  pk.h[4] = f2bf(f1.x); pk.h[5] = f2bf(f1.y); pk.h[6] = f2bf(f1.z); pk.h[7] = f2bf(f1.w);
  return pk.u;
}

// async 16B global -> LDS (wave-uniform base + lane*16 layout)
__device__ __forceinline__ void gl_lds16(const void* g, void* l) {
  __builtin_amdgcn_global_load_lds(
      (const __attribute__((address_space(1))) unsigned*)g,
      (__attribute__((address_space(3))) unsigned*)l, 16, 0, 0);
}

enum { OUT_F32 = 0, OUT_QKV = 1 };

constexpr int BM = 128, BN = 128, BK = 64;

// C[M,N] = alpha * A[M,K] * B[N,K]^T  (NT). B always bf16. A bf16 or fp32.
// grid: (M/128, N/128, batch); 256 threads = 4 waves in 2x2, each 64x64 out.
// LDS tile = [128 rows][8 chunks of 16B]; slot cpos holds global chunk
// cpos ^ (row & 7)  (XOR swizzle -> conflict-free fragment reads).
// Single-buffered, 2 barriers per K-step (R5b-proven fastest structure).
// OUT_QKV: B = [2304][768] = [Wq;Wk;Wv]; grp=n0/768 routes to C0/C1/C2(Vt).
template <bool A_F32, int MODE>
__global__ __launch_bounds__(256)
void gemm128(const void* __restrict__ Ag_, const void* __restrict__ Bg_,
             void* __restrict__ C0, void* __restrict__ C1, void* __restrict__ C2,
             int K, int lda, int ldb, int ldc,
             long long sA, long long sB, long long sC, float alpha) {
  __shared__ u16 As[BM * BK];
  __shared__ u16 Bs[BN * BK];

  const int z  = blockIdx.z;
  const int m0 = blockIdx.x * BM;
  const int n0 = blockIdx.y * BN;

  const int t    = threadIdx.x;
  const int lane = t & 63;
  const int w    = t >> 6;
  const int wm   = (w & 1) * 64;     // wave's 64x64 quadrant
  const int wn   = (w >> 1) * 64;
  const int fr   = lane & 15;        // fragment row
  const int quad = lane >> 4;        // fragment k chunk (16B) within 32-elem k

  const u16* Bp = (const u16*)Bg_ + (size_t)z * (size_t)sB;

  v4f acc[4][4];
#pragma unroll
  for (int i = 0; i < 4; ++i)
#pragma unroll
    for (int j = 0; j < 4; ++j) acc[i][j] = (v4f){0.f, 0.f, 0.f, 0.f};

  for (int kt = 0; kt < K; kt += BK) {
    // --- stage B tile: LDS slot s (=row*8+cpos) gets global chunk cpos^(row&7)
#pragma unroll
    for (int j = 0; j < 4; ++j) {
      const int s   = (w * 4 + j) * 64 + lane;        // LDS 16B-slot, 0..1023
      const int row = s >> 3;
      const int gc  = (s & 7) ^ (row & 7);            // source chunk (swizzled)
      gl_lds16(Bp + (size_t)(n0 + row) * ldb + kt + gc * 8, &Bs[s * 8]);
    }
    // --- stage A tile ---
    if constexpr (A_F32) {
      const float* Ap = (const float*)Ag_ + (size_t)z * (size_t)sA;
#pragma unroll
      for (int j = 0; j < 4; ++j) {
        const int g   = j * 256 + t;                  // source-linear chunk id
        const int row = g >> 3, gc = g & 7;
        const int s   = (g & ~7) | (gc ^ (row & 7));  // swizzled LDS slot
        uint4 pk = pack8(Ap + (size_t)(m0 + row) * lda + kt + gc * 8);
        *(uint4*)&As[s * 8] = pk;
      }
    } else {
      const u16* Ap = (const u16*)Ag_ + (size_t)z * (size_t)sA;
#pragma unroll
      for (int j = 0; j < 4; ++j) {
        const int s   = (w * 4 + j) * 64 + lane;
        const int row = s >> 3;
        const int gc  = (s & 7) ^ (row & 7);
        gl_lds16(Ap + (size_t)(m0 + row) * lda + kt + gc * 8, &As[s * 8]);
      }
    }
    __syncthreads();   // drains vmcnt (global_load_lds) + lgkmcnt (ds_write)

    // --- 32 MFMAs per wave over BK=64 ---
#pragma unroll
    for (int kk = 0; kk < BK; kk += 32) {
      const int kc = (kk >> 3) + quad;                // chunk 0..7
      v8bf af[4], bv[4];
#pragma unroll
      for (int i = 0; i < 4; ++i) {
        const int ra = wm + i * 16 + fr;              // (ra&7)==(fr&7)
        const int rb = wn + i * 16 + fr;
        af[i] = *(const v8bf*)&As[(ra * 8 + (kc ^ (fr & 7))) * 8];
        bv[i] = *(const v8bf*)&Bs[(rb * 8 + (kc ^ (fr & 7))) * 8];
      }
#pragma unroll
      for (int mi = 0; mi < 4; ++mi)
#pragma unroll
        for (int ni = 0; ni < 4; ++ni)
          acc[mi][ni] =
              __builtin_amdgcn_mfma_f32_16x16x32_bf16(af[mi], bv[ni], acc[mi][ni], 0, 0, 0);
    }
    __syncthreads();
  }

  // epilogue: C/D layout col=lane&15, row=(lane>>4)*4+reg
  const int r0 = (lane >> 4) * 4;
#pragma unroll
  for (int mi = 0; mi < 4; ++mi) {
#pragma unroll
    for (int ni = 0; ni < 4; ++ni) {
      v4f v = acc[mi][ni];
      const int grow0 = m0 + wm + mi * 16 + r0;
      const int gcol  = n0 + wn + ni * 16 + fr;
      if constexpr (MODE == OUT_F32) {
        float* C = (float*)C0 + (size_t)z * (size_t)sC;
#pragma unroll
        for (int r = 0; r < 4; ++r)
          C[(size_t)(grow0 + r) * ldc + gcol] = v[r] * alpha;
      } else {  // OUT_QKV: route by weight group (n0 mult of 128, 768=6*128)
        const int grp  = n0 / 768;             // 0=Q, 1=K, 2=V
        const int lcol = gcol - grp * 768;
        if (grp == 0) {
          u16* C = (u16*)C0;
#pragma unroll
          for (int r = 0; r < 4; ++r)
            C[(size_t)(grow0 + r) * 768 + lcol] = f2bf(v[r]);
        } else if (grp == 1) {
          u16* C = (u16*)C1;
#pragma unroll
          for (int r = 0; r < 4; ++r)
            C[(size_t)(grow0 + r) * 768 + lcol] = f2bf(v[r]);
        } else {  // Vt[b][d][s]: rows are 4 consecutive s
          u16* C = (u16*)C2;
          size_t base = (size_t)(grow0 >> 11) * (768ull * 2048ull) +
                        (size_t)lcol * 2048ull + (size_t)(grow0 & 2047);
          ushort4 st;
          st.x = f2bf(v[0]); st.y = f2bf(v[1]); st.z = f2bf(v[2]); st.w = f2bf(v[3]);
          *(ushort4*)&C[base] = st;
        }
      }
    }
  }
}

// fp32 -> bf16 copy, 8 elements/thread
__global__ __launch_bounds__(256)
void cvt_bf16(const float* __restrict__ src, u16* __restrict__ dst, int n8) {
  const int i = blockIdx.x * 256 + threadIdx.x;
  if (i < n8) *(uint4*)(dst + (size_t)i * 8) = pack8(src + (size_t)i * 8);
}

// three small weight matrices in one launch (blockIdx.y selects)
__global__ __launch_bounds__(256)
void cvt3_bf16(const float* __restrict__ s0, const float* __restrict__ s1,
               const float* __restrict__ s2, u16* __restrict__ d0,
               u16* __restrict__ d1, u16* __restrict__ d2, int n8) {
  const float* s = blockIdx.y == 0 ? s0 : blockIdx.y == 1 ? s1 : s2;
  u16*         d = blockIdx.y == 0 ? d0 : blockIdx.y == 1 ? d1 : d2;
  const int i = blockIdx.x * 256 + threadIdx.x;
  if (i < n8) *(uint4*)(d + (size_t)i * 8) = pack8(s + (size_t)i * 8);
}

// in-place softmax over rows of 2048 fp32; one block per row.
// EMIT: also write a bf16 copy of the row to pb (PV's A operand).
template <bool EMIT>
__global__ __launch_bounds__(256) void softmax_rows(float* __restrict__ w,
                                                    u16* __restrict__ pb) {
  float* p = w + (size_t)blockIdx.x * 2048;
  const int t = threadIdx.x;
  float4 a = *(float4*)(p + t * 4);
  float4 b = *(float4*)(p + 1024 + t * 4);

  float mx = fmaxf(fmaxf(fmaxf(a.x, a.y), fmaxf(a.z, a.w)),
                   fmaxf(fmaxf(b.x, b.y), fmaxf(b.z, b.w)));
#pragma unroll
  for (int off = 32; off; off >>= 1) mx = fmaxf(mx, __shfl_xor(mx, off));
  __shared__ float red[4];
  const int wid = t >> 6, ln = t & 63;
  if (ln == 0) red[wid] = mx;
  __syncthreads();
  mx = fmaxf(fmaxf(red[0], red[1]), fmaxf(red[2], red[3]));

  a.x = __expf(a.x - mx); a.y = __expf(a.y - mx);
  a.z = __expf(a.z - mx); a.w = __expf(a.w - mx);
  b.x = __expf(b.x - mx); b.y = __expf(b.y - mx);
  b.z = __expf(b.z - mx); b.w = __expf(b.w - mx);

  float s = a.x + a.y + a.z + a.w + b.x + b.y + b.z + b.w;
#pragma unroll
  for (int off = 32; off; off >>= 1) s += __shfl_xor(s, off);
  __syncthreads();
  if (ln == 0) red[wid] = s;
  __syncthreads();
  s = red[0] + red[1] + red[2] + red[3];

  const float inv = 1.0f / s;
  a.x *= inv; a.y *= inv; a.z *= inv; a.w *= inv;
  b.x *= inv; b.y *= inv; b.z *= inv; b.w *= inv;
  *(float4*)(p + t * 4) = a;
  *(float4*)(p + 1024 + t * 4) = b;

  if constexpr (EMIT) {
    u16* q = pb + (size_t)blockIdx.x * 2048;
    ushort4 ha, hb;
    ha.x = f2bf(a.x); ha.y = f2bf(a.y); ha.z = f2bf(a.z); ha.w = f2bf(a.w);
    hb.x = f2bf(b.x); hb.y = f2bf(b.y); hb.z = f2bf(b.z); hb.w = f2bf(b.w);
    *(ushort4*)(q + t * 4) = ha;
    *(ushort4*)(q + 1024 + t * 4) = hb;
  }
}

extern "C" void kernel_launch(void* const* d_in, const int* in_sizes, int n_in,
                              void* d_out, int out_size, void* d_ws, size_t ws_size,
                              hipStream_t stream) {
  const float* x  = (const float*)d_in[0];
  const float* Wq = (const float*)d_in[1];
  const float* Wk = (const float*)d_in[2];
  const float* Wv = (const float*)d_in[3];
  float* out = (float*)d_out;
  float* wts = out + 8ull * 2048 * 768;   // out1 region (attention weights)

  // bf16 scratch inside d_out (see header comment)
  u16* Qb  = (u16*)d_out;                 // out0: [16384][768]
  u16* Kb  = Qb + 16384ull * 768;         //       [16384][768]
  u16* xb  = (u16*)wts;                   // out1 scratch: [16384][768]
  u16* Wqb = xb + 16384ull * 768;         //               [768][768] x3 (contig)
  u16* Wkb = Wqb + 768ull * 768;
  u16* Wvb = Wkb + 768ull * 768;
  u16* Vt  = (u16*)d_ws;                  // ws: [8][768][2048] (25.2 MB)
  u16* Pb  = Vt + 8ull * 768 * 2048;      // ws: [8][2048][2048] bf16 (67.1 MB)

  const size_t VT_BYTES = 8ull * 768 * 2048 * 2;
  const size_t PB_BYTES = 8ull * 2048 * 2048 * 2;
  const bool   pb_ok    = ws_size >= VT_BYTES + PB_BYTES;

  const dim3 blk(256, 1, 1);
  const float isq = 1.0f / sqrtf(768.0f);

  // pre-convert inputs to bf16
  cvt_bf16<<<dim3(6144, 1, 1), blk, 0, stream>>>(x, xb, 16384 * 768 / 8);
  cvt3_bf16<<<dim3(288, 3, 1), blk, 0, stream>>>(Wq, Wk, Wv, Wqb, Wkb, Wvb,
                                                 768 * 768 / 8);

  // fused QKV: M=16384, N=2304 (=[Wq;Wk;Wv]), K=768, one launch, 128^2 tiles
  gemm128<false, OUT_QKV><<<dim3(128, 18, 1), blk, 0, stream>>>(
      xb, Wqb, (void*)Qb, (void*)Kb, (void*)Vt, 768, 768, 768, 768,
      0, 0, 0, 1.0f);

  // scores: per batch M=N=2048, K=768 -> wts fp32 * 1/sqrt(D)
  gemm128<false, OUT_F32><<<dim3(16, 16, 8), blk, 0, stream>>>(
      Qb, Kb, (void*)wts, nullptr, nullptr, 768, 768, 768, 2048,
      2048ll * 768, 2048ll * 768, 2048ll * 2048, isq);

  // softmax in place over 16384 rows (+ bf16 emit for PV if ws allows)
  if (pb_ok) {
    softmax_rows<true><<<dim3(16384, 1, 1), blk, 0, stream>>>(wts, Pb);
    // PV fast path: all-bf16. per batch M=2048, N=768, K=2048
    gemm128<false, OUT_F32><<<dim3(16, 6, 8), blk, 0, stream>>>(
        Pb, Vt, (void*)out, nullptr, nullptr, 2048, 2048, 2048, 768,
        2048ll * 2048, 768ll * 2048, 2048ll * 768, 1.0f);
  } else {
    softmax_rows<false><<<dim3(16384, 1, 1), blk, 0, stream>>>(wts, nullptr);
    // fallback: A=attn fp32 (convert-staged in-GEMM)
    gemm128<true, OUT_F32><<<dim3(16, 6, 8), blk, 0, stream>>>(
        wts, Vt, (void*)out, nullptr, nullptr, 2048, 2048, 2048, 768,
        2048ll * 2048, 768ll * 2048, 2048ll * 768, 1.0f);
  }
}